// Round 1
// baseline (303.236 us; speedup 1.0000x reference)
//
#include <hip/hip_runtime.h>

#define KSZ 11
#define HALO 5
#define TILE 32
#define SMW (TILE + 2 * HALO) /* 42 */
#define THREADS 256
#define PX_PER_THREAD ((TILE * TILE) / THREADS) /* 4 */

// Fused SSIM tile kernel: separable 11x11 Gaussian blur of {x, y, x^2, y^2, xy}
// over one 32x32 output tile of one (n,c) plane, then SSIM map + block-level
// partial sum. Zero padding matches JAX conv padding=[(5,5),(5,5)].
__global__ __launch_bounds__(THREADS) void ssim_tile_kernel(
    const float* __restrict__ x, const float* __restrict__ y,
    float* __restrict__ partial, int W, int H)
{
    __shared__ float lx[SMW * SMW];
    __shared__ float ly[SMW * SMW];
    __shared__ float hbuf[SMW * TILE];
    __shared__ float wsum[THREADS / 64];

    const int tid = threadIdx.x;
    const int tilesPerRow = W / TILE;
    const int tileR = (blockIdx.x / tilesPerRow) * TILE;
    const int tileC = (blockIdx.x % tilesPerRow) * TILE;
    const size_t base = (size_t)blockIdx.y * (size_t)W * (size_t)H;

    // Gaussian weights (f32, matches jnp: exp(-((c/1.5)^2)/2), normalized)
    float w[KSZ];
    {
        float s = 0.f;
#pragma unroll
        for (int i = 0; i < KSZ; ++i) {
            float c = (float)(i - HALO);
            float t = c * (1.0f / 1.5f);
            w[i] = expf(-0.5f * t * t);
            s += w[i];
        }
        float inv = 1.0f / s;
#pragma unroll
        for (int i = 0; i < KSZ; ++i) w[i] *= inv;
    }

    // Stage raw x,y tile (with halo) into LDS; zero-fill out-of-bounds.
    for (int i = tid; i < SMW * SMW; i += THREADS) {
        int r = i / SMW, c = i - r * SMW;
        int gr = tileR - HALO + r;
        int gc = tileC - HALO + c;
        float vx = 0.f, vy = 0.f;
        if (gr >= 0 && gr < H && gc >= 0 && gc < W) {
            size_t off = base + (size_t)gr * W + (size_t)gc;
            vx = x[off];
            vy = y[off];
        }
        lx[i] = vx;
        ly[i] = vy;
    }
    __syncthreads();

    // Per-thread accumulators for the 5 blurred signals x 4 pixels.
    // s-loop MUST be unrolled so acc indexing is compile-time (no scratch).
    float acc[5][PX_PER_THREAD];

#pragma unroll
    for (int s = 0; s < 5; ++s) {
        // Horizontal pass: SMW rows x TILE cols
        for (int i = tid; i < SMW * TILE; i += THREADS) {
            int r = i / TILE, c = i - r * TILE;
            const float* rowx = &lx[r * SMW + c];
            const float* rowy = &ly[r * SMW + c];
            float sum = 0.f;
#pragma unroll
            for (int k = 0; k < KSZ; ++k) {
                float a = rowx[k];
                float b = rowy[k];
                float v;
                if (s == 0)      v = a;
                else if (s == 1) v = b;
                else if (s == 2) v = a * a;
                else if (s == 3) v = b * b;
                else             v = a * b;
                sum += w[k] * v;
            }
            hbuf[i] = sum;
        }
        __syncthreads();

        // Vertical pass: TILE x TILE outputs, 4 per thread
#pragma unroll
        for (int t = 0; t < PX_PER_THREAD; ++t) {
            int pi = tid + t * THREADS;
            int r = pi / TILE, c = pi - (pi / TILE) * TILE;
            float sum = 0.f;
#pragma unroll
            for (int k = 0; k < KSZ; ++k) sum += w[k] * hbuf[(r + k) * TILE + c];
            acc[s][t] = sum;
        }
        __syncthreads();
    }

    // SSIM map + per-thread sum
    const float c1 = 0.01f * 0.01f;
    const float c2 = 0.03f * 0.03f;
    float bsum = 0.f;
#pragma unroll
    for (int t = 0; t < PX_PER_THREAD; ++t) {
        float ux = acc[0][t], uy = acc[1][t];
        float uxx = acc[2][t], uyy = acc[3][t], uxy = acc[4][t];
        float vx = uxx - ux * ux;
        float vy = uyy - uy * uy;
        float vxy = uxy - ux * uy;
        float num = (2.f * ux * uy + c1) * (2.f * vxy + c2);
        float den = (ux * ux + uy * uy + c1) * (vx + vy + c2);
        bsum += num / (den + 1e-12f);
    }

    // Wave (64-lane) shuffle reduce, then cross-wave via LDS
#pragma unroll
    for (int off = 32; off > 0; off >>= 1) bsum += __shfl_down(bsum, off, 64);
    int lane = tid & 63, wid = tid >> 6;
    if (lane == 0) wsum[wid] = bsum;
    __syncthreads();
    if (tid == 0) {
        float tot = 0.f;
#pragma unroll
        for (int i = 0; i < THREADS / 64; ++i) tot += wsum[i];
        partial[(size_t)blockIdx.y * gridDim.x + blockIdx.x] = tot;
    }
}

// Final deterministic reduction: n partials -> out[0] = 1 - sum/count
__global__ __launch_bounds__(256) void ssim_reduce_kernel(
    const float* __restrict__ partial, int n, float* __restrict__ out,
    double inv_count)
{
    __shared__ double ws[4];
    double s = 0.0;
    for (int i = threadIdx.x; i < n; i += 256) s += (double)partial[i];
#pragma unroll
    for (int off = 32; off > 0; off >>= 1) s += __shfl_down(s, off, 64);
    int lane = threadIdx.x & 63, wid = threadIdx.x >> 6;
    if (lane == 0) ws[wid] = s;
    __syncthreads();
    if (threadIdx.x == 0) {
        double tot = ws[0] + ws[1] + ws[2] + ws[3];
        out[0] = (float)(1.0 - tot * inv_count);
    }
}

extern "C" void kernel_launch(void* const* d_in, const int* in_sizes, int n_in,
                              void* d_out, int out_size, void* d_ws, size_t ws_size,
                              hipStream_t stream) {
    const float* x = (const float*)d_in[0];
    const float* y = (const float*)d_in[1];
    float* partial = (float*)d_ws;

    const int W = 512, H = 512;
    const int N = 32, C = 2;
    const int tilesPerPlane = (W / TILE) * (H / TILE); // 256
    const int planes = N * C;                          // 64

    dim3 grid(tilesPerPlane, planes);
    ssim_tile_kernel<<<grid, THREADS, 0, stream>>>(x, y, partial, W, H);

    const int nPartial = tilesPerPlane * planes; // 16384
    const double inv_count = 1.0 / ((double)N * C * W * H);
    ssim_reduce_kernel<<<1, 256, 0, stream>>>(partial, nPartial, (float*)d_out,
                                              inv_count);
}

// Round 2
// 168.417 us; speedup vs baseline: 1.8005x; 1.8005x over previous
//
#include <hip/hip_runtime.h>

#define KSZ 11
#define HALO 5
#define TILE 32
#define SMW (TILE + 2 * HALO) /* 42 */
#define THREADS 256

// Normalized 1-D Gaussian, sigma=1.5, K=11 (computed in double, f32-rounded).
// Compile-time constants: fold into immediates/SGPRs, zero VGPR cost.
#define W0 1.0283800e-03f
#define W1 7.5987000e-03f
#define W2 3.6000800e-02f
#define W3 1.0936070e-01f
#define W4 2.1300550e-01f
#define W5 2.6601170e-01f

__global__ __launch_bounds__(THREADS) void ssim_tile_kernel(
    const float* __restrict__ x, const float* __restrict__ y,
    float* __restrict__ partial, int W, int H)
{
    __shared__ float2 lxy[SMW * SMW];                       // 14.1 KB
    __shared__ __align__(16) float hbuf[5][TILE * SMW];     // 26.9 KB
    __shared__ float wsum[THREADS / 64];

    const float w[KSZ] = {W0, W1, W2, W3, W4, W5, W4, W3, W2, W1, W0};

    const int tid = threadIdx.x;
    const int tilesPerRow = W / TILE;
    const int tileR = (blockIdx.x / tilesPerRow) * TILE;
    const int tileC = (blockIdx.x % tilesPerRow) * TILE;
    const size_t base = (size_t)blockIdx.y * (size_t)W * (size_t)H;

    // ---- Stage raw x,y tile (with halo) as interleaved float2 ----
    for (int i = tid; i < SMW * SMW; i += THREADS) {
        int r = i / SMW, c = i - r * SMW;
        int gr = tileR - HALO + r;
        int gc = tileC - HALO + c;
        float vx = 0.f, vy = 0.f;
        if (gr >= 0 && gr < H && gc >= 0 && gc < W) {
            size_t off = base + (size_t)gr * W + (size_t)gc;
            vx = x[off];
            vy = y[off];
        }
        lxy[i] = make_float2(vx, vy);
    }
    __syncthreads();

    // ---- Horizontal pass: all 5 signals fused, 4 consecutive cols/item ----
    // 42 rows x 8 col-groups = 336 items; each loads a 14-wide float2 window.
    for (int wi = tid; wi < SMW * 8; wi += THREADS) {
        int r = wi >> 3;
        int c0 = (wi & 7) << 2;
        const float2* row = &lxy[r * SMW + c0];

        float2 v[14];
#pragma unroll
        for (int k = 0; k < 14; ++k) v[k] = row[k];
        float aa[14], bb[14], ab[14];
#pragma unroll
        for (int k = 0; k < 14; ++k) {
            aa[k] = v[k].x * v[k].x;
            bb[k] = v[k].y * v[k].y;
            ab[k] = v[k].x * v[k].y;
        }

        float s0[4] = {0, 0, 0, 0}, s1[4] = {0, 0, 0, 0}, s2[4] = {0, 0, 0, 0};
        float s3[4] = {0, 0, 0, 0}, s4[4] = {0, 0, 0, 0};
#pragma unroll
        for (int k = 0; k < KSZ; ++k) {
#pragma unroll
            for (int j = 0; j < 4; ++j) {
                s0[j] += w[k] * v[k + j].x;
                s1[j] += w[k] * v[k + j].y;
                s2[j] += w[k] * aa[k + j];
                s3[j] += w[k] * bb[k + j];
                s4[j] += w[k] * ab[k + j];
            }
        }
        int o = r * TILE + c0;
        *(float4*)&hbuf[0][o] = make_float4(s0[0], s0[1], s0[2], s0[3]);
        *(float4*)&hbuf[1][o] = make_float4(s1[0], s1[1], s1[2], s1[3]);
        *(float4*)&hbuf[2][o] = make_float4(s2[0], s2[1], s2[2], s2[3]);
        *(float4*)&hbuf[3][o] = make_float4(s3[0], s3[1], s3[2], s3[3]);
        *(float4*)&hbuf[4][o] = make_float4(s4[0], s4[1], s4[2], s4[3]);
    }
    __syncthreads();

    // ---- Vertical pass: thread owns (col c, rows r0..r0+3), slide window ----
    const int c = tid & (TILE - 1);
    const int r0 = (tid >> 5) << 2;

    float acc[5][4];
#pragma unroll
    for (int s = 0; s < 5; ++s) {
        float win[14];
#pragma unroll
        for (int k = 0; k < 14; ++k) win[k] = hbuf[s][(r0 + k) * TILE + c];
#pragma unroll
        for (int j = 0; j < 4; ++j) {
            float t = 0.f;
#pragma unroll
            for (int k = 0; k < KSZ; ++k) t += w[k] * win[j + k];
            acc[s][j] = t;
        }
    }

    // ---- SSIM map + per-thread sum ----
    const float c1 = 0.01f * 0.01f;
    const float c2 = 0.03f * 0.03f;
    float bsum = 0.f;
#pragma unroll
    for (int j = 0; j < 4; ++j) {
        float ux = acc[0][j], uy = acc[1][j];
        float uxx = acc[2][j], uyy = acc[3][j], uxy = acc[4][j];
        float vx = uxx - ux * ux;
        float vy = uyy - uy * uy;
        float vxy = uxy - ux * uy;
        float num = (2.f * ux * uy + c1) * (2.f * vxy + c2);
        float den = (ux * ux + uy * uy + c1) * (vx + vy + c2);
        bsum += num / (den + 1e-12f);
    }

    // ---- Wave shuffle reduce, cross-wave via LDS ----
#pragma unroll
    for (int off = 32; off > 0; off >>= 1) bsum += __shfl_down(bsum, off, 64);
    int lane = tid & 63, wid = tid >> 6;
    if (lane == 0) wsum[wid] = bsum;
    __syncthreads();
    if (tid == 0) {
        float tot = 0.f;
#pragma unroll
        for (int i = 0; i < THREADS / 64; ++i) tot += wsum[i];
        partial[(size_t)blockIdx.y * gridDim.x + blockIdx.x] = tot;
    }
}

// Final deterministic reduction: n partials -> out[0] = 1 - sum/count
__global__ __launch_bounds__(256) void ssim_reduce_kernel(
    const float* __restrict__ partial, int n, float* __restrict__ out,
    double inv_count)
{
    __shared__ double ws[4];
    double s = 0.0;
    for (int i = threadIdx.x; i < n; i += 256) s += (double)partial[i];
#pragma unroll
    for (int off = 32; off > 0; off >>= 1) s += __shfl_down(s, off, 64);
    int lane = threadIdx.x & 63, wid = threadIdx.x >> 6;
    if (lane == 0) ws[wid] = s;
    __syncthreads();
    if (threadIdx.x == 0) {
        double tot = ws[0] + ws[1] + ws[2] + ws[3];
        out[0] = (float)(1.0 - tot * inv_count);
    }
}

extern "C" void kernel_launch(void* const* d_in, const int* in_sizes, int n_in,
                              void* d_out, int out_size, void* d_ws, size_t ws_size,
                              hipStream_t stream) {
    const float* x = (const float*)d_in[0];
    const float* y = (const float*)d_in[1];
    float* partial = (float*)d_ws;

    const int W = 512, H = 512;
    const int N = 32, C = 2;
    const int tilesPerPlane = (W / TILE) * (H / TILE); // 256
    const int planes = N * C;                          // 64

    dim3 grid(tilesPerPlane, planes);
    ssim_tile_kernel<<<grid, THREADS, 0, stream>>>(x, y, partial, W, H);

    const int nPartial = tilesPerPlane * planes; // 16384
    const double inv_count = 1.0 / ((double)N * C * W * H);
    ssim_reduce_kernel<<<1, 256, 0, stream>>>(partial, nPartial, (float*)d_out,
                                              inv_count);
}

// Round 3
// 136.947 us; speedup vs baseline: 2.2143x; 1.2298x over previous
//
#include <hip/hip_runtime.h>

#define KSZ 11
#define HALO 5
#define TILE 32
#define SMW (TILE + 2 * HALO) /* 42 */
#define LSTR 43               /* odd float2 stride: spreads bank pairs */
#define THREADS 256

// Normalized 1-D Gaussian, sigma=1.5, K=11.
#define W0 1.0283800e-03f
#define W1 7.5987000e-03f
#define W2 3.6000800e-02f
#define W3 1.0936070e-01f
#define W4 2.1300550e-01f
#define W5 2.6601170e-01f

__global__ __launch_bounds__(THREADS) void ssim_tile_kernel(
    const float* __restrict__ x, const float* __restrict__ y,
    float* __restrict__ partial, int W, int H)
{
    // 4 blurred signals: ux, uy, p = x^2+y^2, q = x*y
    __shared__ float2 lxy[SMW * LSTR];                    // 14.4 KB
    __shared__ __align__(16) float hbuf[4][SMW * TILE];   // 21.5 KB
    __shared__ float wsum[THREADS / 64];

    const float w[KSZ] = {W0, W1, W2, W3, W4, W5, W4, W3, W2, W1, W0};

    const int tid = threadIdx.x;
    const int tilesPerRow = W / TILE;
    const int tileR = (blockIdx.x / tilesPerRow) * TILE;
    const int tileC = (blockIdx.x % tilesPerRow) * TILE;
    const size_t base = (size_t)blockIdx.y * (size_t)W * (size_t)H;

    // ---- Stage raw x,y tile (with halo) as interleaved float2 ----
    const bool interior = (tileR >= HALO) && (tileR + TILE + HALO <= H) &&
                          (tileC >= HALO) && (tileC + TILE + HALO <= W);
    if (interior) {
        const float* xb = x + base + (size_t)(tileR - HALO) * W + (tileC - HALO);
        const float* yb = y + base + (size_t)(tileR - HALO) * W + (tileC - HALO);
        for (int i = tid; i < SMW * SMW; i += THREADS) {
            int r = i / SMW, c = i - r * SMW;
            int g = r * W + c;
            lxy[r * LSTR + c] = make_float2(xb[g], yb[g]);
        }
    } else {
        for (int i = tid; i < SMW * SMW; i += THREADS) {
            int r = i / SMW, c = i - r * SMW;
            int gr = tileR - HALO + r;
            int gc = tileC - HALO + c;
            float vx = 0.f, vy = 0.f;
            if (gr >= 0 && gr < H && gc >= 0 && gc < W) {
                size_t off = base + (size_t)gr * W + (size_t)gc;
                vx = x[off];
                vy = y[off];
            }
            lxy[r * LSTR + c] = make_float2(vx, vy);
        }
    }
    __syncthreads();

    // ---- Horizontal pass: 4 signals fused, 4 consecutive cols/item ----
    // 42 rows x 8 col-groups = 336 items; each loads a 14-wide float2 window.
    for (int wi = tid; wi < SMW * 8; wi += THREADS) {
        int r = wi >> 3;
        int c0 = (wi & 7) << 2;
        const float2* row = &lxy[r * LSTR + c0];

        float2 v[14];
#pragma unroll
        for (int k = 0; k < 14; ++k) v[k] = row[k];
        float pp[14], qq[14];
#pragma unroll
        for (int k = 0; k < 14; ++k) {
            pp[k] = v[k].x * v[k].x + v[k].y * v[k].y;
            qq[k] = v[k].x * v[k].y;
        }

        float s0[4] = {0, 0, 0, 0}, s1[4] = {0, 0, 0, 0};
        float s2[4] = {0, 0, 0, 0}, s3[4] = {0, 0, 0, 0};
#pragma unroll
        for (int k = 0; k < KSZ; ++k) {
#pragma unroll
            for (int j = 0; j < 4; ++j) {
                s0[j] += w[k] * v[k + j].x;
                s1[j] += w[k] * v[k + j].y;
                s2[j] += w[k] * pp[k + j];
                s3[j] += w[k] * qq[k + j];
            }
        }
        int o = r * TILE + c0;
        *(float4*)&hbuf[0][o] = make_float4(s0[0], s0[1], s0[2], s0[3]);
        *(float4*)&hbuf[1][o] = make_float4(s1[0], s1[1], s1[2], s1[3]);
        *(float4*)&hbuf[2][o] = make_float4(s2[0], s2[1], s2[2], s2[3]);
        *(float4*)&hbuf[3][o] = make_float4(s3[0], s3[1], s3[2], s3[3]);
    }
    __syncthreads();

    // ---- Vertical pass: thread owns (col c, rows r0..r0+3) ----
    const int c = tid & (TILE - 1);
    const int r0 = (tid >> 5) << 2;

    float acc[4][4];
#pragma unroll
    for (int s = 0; s < 4; ++s) {
        float win[14];
#pragma unroll
        for (int k = 0; k < 14; ++k) win[k] = hbuf[s][(r0 + k) * TILE + c];
#pragma unroll
        for (int j = 0; j < 4; ++j) {
            float t = 0.f;
#pragma unroll
            for (int k = 0; k < KSZ; ++k) t += w[k] * win[j + k];
            acc[s][j] = t;
        }
    }

    // ---- SSIM map + per-thread sum ----
    const float c1 = 0.01f * 0.01f;
    const float c2 = 0.03f * 0.03f;
    float bsum = 0.f;
#pragma unroll
    for (int j = 0; j < 4; ++j) {
        float ux = acc[0][j], uy = acc[1][j];
        float up = acc[2][j], uq = acc[3][j];
        float sumsq = ux * ux + uy * uy;            // ux^2 + uy^2
        float vsum = up - sumsq;                    // vx + vy
        float vxy = uq - ux * uy;
        float num = (2.f * ux * uy + c1) * (2.f * vxy + c2);
        float den = (sumsq + c1) * (vsum + c2);
        bsum += num * __builtin_amdgcn_rcpf(den + 1e-12f);
    }

    // ---- Wave shuffle reduce, cross-wave via LDS ----
#pragma unroll
    for (int off = 32; off > 0; off >>= 1) bsum += __shfl_down(bsum, off, 64);
    int lane = tid & 63, wid = tid >> 6;
    if (lane == 0) wsum[wid] = bsum;
    __syncthreads();
    if (tid == 0) {
        float tot = 0.f;
#pragma unroll
        for (int i = 0; i < THREADS / 64; ++i) tot += wsum[i];
        partial[(size_t)blockIdx.y * gridDim.x + blockIdx.x] = tot;
    }
}

// Final deterministic reduction: n partials -> out[0] = 1 - sum/count
__global__ __launch_bounds__(256) void ssim_reduce_kernel(
    const float* __restrict__ partial, int n, float* __restrict__ out,
    double inv_count)
{
    __shared__ double ws[4];
    double s = 0.0;
    for (int i = threadIdx.x; i < n; i += 256) s += (double)partial[i];
#pragma unroll
    for (int off = 32; off > 0; off >>= 1) s += __shfl_down(s, off, 64);
    int lane = threadIdx.x & 63, wid = threadIdx.x >> 6;
    if (lane == 0) ws[wid] = s;
    __syncthreads();
    if (threadIdx.x == 0) {
        double tot = ws[0] + ws[1] + ws[2] + ws[3];
        out[0] = (float)(1.0 - tot * inv_count);
    }
}

extern "C" void kernel_launch(void* const* d_in, const int* in_sizes, int n_in,
                              void* d_out, int out_size, void* d_ws, size_t ws_size,
                              hipStream_t stream) {
    const float* x = (const float*)d_in[0];
    const float* y = (const float*)d_in[1];
    float* partial = (float*)d_ws;

    const int W = 512, H = 512;
    const int N = 32, C = 2;
    const int tilesPerPlane = (W / TILE) * (H / TILE); // 256
    const int planes = N * C;                          // 64

    dim3 grid(tilesPerPlane, planes);
    ssim_tile_kernel<<<grid, THREADS, 0, stream>>>(x, y, partial, W, H);

    const int nPartial = tilesPerPlane * planes; // 16384
    const double inv_count = 1.0 / ((double)N * C * W * H);
    ssim_reduce_kernel<<<1, 256, 0, stream>>>(partial, nPartial, (float*)d_out,
                                              inv_count);
}